// Round 8
// baseline (84.703 us; speedup 1.0000x reference)
//
#include <hip/hip_runtime.h>
#include <math.h>

#define NG 2048
#define FEATN 128
#define LOG2E 1.4426950408889634f

typedef unsigned long long u64;

// ws float4-offsets: RAW_A f4[0..2048) {u,v,rx,ry} | RAW_B f4[2048..4096) {a2,b2,c2,op}
//                    RAW_C f4[4096..6144) {r,g,b,0} | TZ float[24576..26624)
#define TZ_FOFF 24576

__device__ __forceinline__ float sigmoidf_(float z) { return 1.0f / (1.0f + expf(-z)); }

__global__ __launch_bounds__(64) void k_pre(
    const float* __restrict__ x, const float* __restrict__ pts, const float* __restrict__ vm,
    const float* __restrict__ w_shs, const float* __restrict__ b_shs,
    const float* __restrict__ w_scale, const float* __restrict__ b_scale,
    const float* __restrict__ w_xyz, const float* __restrict__ b_xyz,
    const float* __restrict__ w_opac, const float* __restrict__ b_opac,
    const float* __restrict__ w_rot, const float* __restrict__ b_rot,
    float* __restrict__ ws)
{
    __shared__ float sw[14 * FEATN];
    int tid = threadIdx.x;
    for (int i = tid; i < 14 * FEATN; i += 64) {
        int r = i >> 7, c0 = i & 127;
        float v;
        if (r < 3)       v = w_shs[r * FEATN + c0];
        else if (r < 6)  v = w_scale[(r - 3) * FEATN + c0];
        else if (r < 9)  v = w_xyz[(r - 6) * FEATN + c0];
        else if (r == 9) v = w_opac[c0];
        else             v = w_rot[(r - 10) * FEATN + c0];
        sw[i] = v;
    }
    __syncthreads();
    int g = blockIdx.x * 64 + tid;

    float acc[14];
#pragma unroll
    for (int j = 0; j < 14; j++) acc[j] = 0.0f;
    const float4* x4 = (const float4*)(x + (size_t)g * FEATN);
#pragma unroll 4
    for (int k4 = 0; k4 < FEATN / 4; k4++) {
        float4 xv = x4[k4];
#pragma unroll
        for (int j = 0; j < 14; j++) {
            const float* wr = &sw[j * FEATN + k4 * 4];
            acc[j] += xv.x * wr[0] + xv.y * wr[1] + xv.z * wr[2] + xv.w * wr[3];
        }
    }

    float r0 = sigmoidf_(acc[0] + b_shs[0]);
    float r1 = sigmoidf_(acc[1] + b_shs[1]);
    float r2 = sigmoidf_(acc[2] + b_shs[2]);
    float s0 = fminf(expf(acc[3] + b_scale[0]), 0.2f);
    float s1 = fminf(expf(acc[4] + b_scale[1]), 0.2f);
    float s2 = fminf(expf(acc[5] + b_scale[2]), 0.2f);
    float o0 = (sigmoidf_(acc[6] + b_xyz[0]) - 0.5f) * 0.05f;
    float o1 = (sigmoidf_(acc[7] + b_xyz[1]) - 0.5f) * 0.05f;
    float o2 = (sigmoidf_(acc[8] + b_xyz[2]) - 0.5f) * 0.05f;
    float opac = sigmoidf_(acc[9] + b_opac[0]);
    float qw = acc[10] + b_rot[0];
    float qx = acc[11] + b_rot[1];
    float qy = acc[12] + b_rot[2];
    float qz = acc[13] + b_rot[3];
    float qn = sqrtf(qw * qw + qx * qx + qy * qy + qz * qz);
    qw /= qn; qx /= qn; qy /= qn; qz /= qn;

    float R[3][3];
    R[0][0] = 1.f - 2.f * (qy * qy + qz * qz);
    R[0][1] = 2.f * (qx * qy - qw * qz);
    R[0][2] = 2.f * (qx * qz + qw * qy);
    R[1][0] = 2.f * (qx * qy + qw * qz);
    R[1][1] = 1.f - 2.f * (qx * qx + qz * qz);
    R[1][2] = 2.f * (qy * qz - qw * qx);
    R[2][0] = 2.f * (qx * qz - qw * qy);
    R[2][1] = 2.f * (qy * qz + qw * qx);
    R[2][2] = 1.f - 2.f * (qx * qx + qy * qy);

    float sq[3] = { s0 * s0, s1 * s1, s2 * s2 };
    float cov[3][3];
#pragma unroll
    for (int i = 0; i < 3; i++)
#pragma unroll
        for (int k = 0; k < 3; k++)
            cov[i][k] = R[i][0] * sq[0] * R[k][0] + R[i][1] * sq[1] * R[k][1] + R[i][2] * sq[2] * R[k][2];

    float Rv[3][3], tv[3];
#pragma unroll
    for (int i = 0; i < 3; i++) {
#pragma unroll
        for (int j = 0; j < 3; j++) Rv[i][j] = vm[i * 4 + j];
        tv[i] = vm[i * 4 + 3];
    }
    float X0 = pts[g * 3 + 0] + o0;
    float X1 = pts[g * 3 + 1] + o1;
    float X2 = pts[g * 3 + 2] + o2;
    float p0 = Rv[0][0] * X0 + Rv[0][1] * X1 + Rv[0][2] * X2 + tv[0];
    float p1 = Rv[1][0] * X0 + Rv[1][1] * X1 + Rv[1][2] * X2 + tv[1];
    float p2 = Rv[2][0] * X0 + Rv[2][1] * X1 + Rv[2][2] * X2 + tv[2];
    float tz = fmaxf(p2, 0.001f);
    float u = 128.0f * p0 / tz + 64.0f;
    float v = 128.0f * p1 / tz + 64.0f;

    float j00 = 128.0f / tz, j02 = -128.0f * p0 / (tz * tz);
    float j11 = 128.0f / tz, j12 = -128.0f * p1 / (tz * tz);
    float M0[3], M1[3];
#pragma unroll
    for (int k = 0; k < 3; k++) {
        M0[k] = j00 * Rv[0][k] + j02 * Rv[2][k];
        M1[k] = j11 * Rv[1][k] + j12 * Rv[2][k];
    }
    float t0[3], t1[3];
#pragma unroll
    for (int k = 0; k < 3; k++) {
        t0[k] = M0[0] * cov[0][k] + M0[1] * cov[1][k] + M0[2] * cov[2][k];
        t1[k] = M1[0] * cov[0][k] + M1[1] * cov[1][k] + M1[2] * cov[2][k];
    }
    float A = t0[0] * M0[0] + t0[1] * M0[1] + t0[2] * M0[2] + 0.3f;
    float B = t0[0] * M1[0] + t0[1] * M1[1] + t0[2] * M1[2];
    float C = t1[0] * M1[0] + t1[1] * M1[1] + t1[2] * M1[2] + 0.3f;
    float det = A * C - B * B + 1e-12f;
    float cA = C / det, cB = -B / det, cC = A / det;

    if (p2 <= 0.01f) opac = 0.0f;   // vis mask folded into opacity

    // conservative bounding half-extents for alpha >= 1/255
    float rx, ry;
    if (opac >= 1.0f / 255.0f) {
        float L = 2.0f * logf(255.0f * opac);
        rx = sqrtf(L * A) + 0.5f;
        ry = sqrtf(L * C) + 0.5f;
    } else {
        rx = -1e9f; ry = -1e9f;   // never kept
    }

    float4* ws4 = (float4*)ws;
    ws4[0 * NG + g] = make_float4(u, v, rx, ry);
    ws4[1 * NG + g] = make_float4(-0.5f * LOG2E * cA, -LOG2E * cB, -0.5f * LOG2E * cC, opac);
    ws4[2 * NG + g] = make_float4(r0, r1, r2, 0.0f);
    ws[TZ_FOFF + g] = tz;
}

// one block per 8x8 tile: cull (unsorted) -> local rank sort of survivors ->
// depth-ordered composite. Per-tile sorted subsequence == global order restricted
// to this tile's survivors => identical math to the global sort.
__global__ __launch_bounds__(64) void k_render(const float* __restrict__ ws, float* __restrict__ out)
{
    __shared__ u64 slist[NG];        // survivor keys (tz_bits<<32 | g)
    __shared__ int sort_g[NG];       // depth-ordered survivor indices
    __shared__ float comp[64 * 12];  // staged params for one composite round

    const int lane = threadIdx.x;
    const int bid = blockIdx.x;
    const float4* RA = (const float4*)ws;
    const float4* RB = RA + NG;
    const float4* RC = RA + 2 * NG;
    const float* TZ = ws + TZ_FOFF;

    int tx0 = (bid & 15) << 3, ty0 = (bid >> 4) << 3;
    float x0 = tx0 + 0.5f, x1 = tx0 + 7.5f;
    float y0 = ty0 + 0.5f, y1 = ty0 + 7.5f;
    u64 lmask = (1ull << lane) - 1ull;

    // ---- cull + append survivors (g-ascending order preserved) ----
    int n = 0;
    float4 na = RA[lane];
    float ntz = TZ[lane];
    for (int r = 0; r < NG / 64; ++r) {
        float4 a = na;
        float tz = ntz;
        if (r + 1 < NG / 64) {            // prefetch next round
            na = RA[(r + 1) * 64 + lane];
            ntz = TZ[(r + 1) * 64 + lane];
        }
        bool keep = (a.x + a.z >= x0) && (a.x - a.z <= x1) &&
                    (a.y + a.w >= y0) && (a.y - a.w <= y1);
        u64 m = __ballot(keep);
        if (keep) {
            int pos = n + __popcll(m & lmask);
            slist[pos] = ((u64)__float_as_uint(tz) << 32) | (unsigned)(r * 64 + lane);
        }
        n += __popcll(m);
    }
    __syncthreads();

    // ---- local stable depth sort (rank sort; keys distinct) ----
    for (int i = lane; i < n; i += 64) {
        u64 ki = slist[i];
        int cnt = 0;
        int j = 0;
        for (; j + 4 <= n; j += 4) {
            cnt += (slist[j + 0] < ki) ? 1 : 0;
            cnt += (slist[j + 1] < ki) ? 1 : 0;
            cnt += (slist[j + 2] < ki) ? 1 : 0;
            cnt += (slist[j + 3] < ki) ? 1 : 0;
        }
        for (; j < n; ++j) cnt += (slist[j] < ki) ? 1 : 0;
        sort_g[cnt] = (int)(unsigned)(ki & 0xffffffffu);
    }
    __syncthreads();

    // ---- depth-ordered composite ----
    float gx = x0 + (float)(lane & 7);
    float gy = y0 + (float)(lane >> 3);
    float T = 1.0f, oR = 0.0f, oG = 0.0f, oB = 0.0f;
    for (int base = 0; base < n; base += 64) {
        int nr = min(64, n - base);
        if (lane < nr) {
            int g = sort_g[base + lane];
            float4 a = RA[g];
            float4 b = RB[g];
            float4 c = RC[g];
            float* e = comp + lane * 12;
            ((float4*)e)[0] = make_float4(a.x, a.y, b.x, b.y);   // u,v,a2,b2
            ((float4*)e)[1] = make_float4(b.z, b.w, c.x, c.y);   // c2,op,r,g
            e[8] = c.z;                                          // b
        }
        __syncthreads();
        for (int i = 0; i < nr; ++i) {
            const float* e = comp + i * 12;
            float4 e0 = ((const float4*)e)[0];
            float4 e1 = ((const float4*)e)[1];
            float bl = e[8];
            float dx = gx - e0.x, dy = gy - e0.y;
            float pw = dx * (e0.z * dx + e0.w * dy) + e1.x * dy * dy;  // log2-domain
            pw = fminf(pw, 0.0f);
            float al = fminf(0.99f, e1.y * exp2f(pw));
            al = (al < 1.0f / 255.0f) ? 0.0f : al;
            float w = al * T;
            oR += w * e1.z;
            oG += w * e1.w;
            oB += w * bl;
            T -= al * T;
        }
        __syncthreads();
        if (__ballot(T >= 1.5e-5f) == 0ull) break;   // all 64 pixels saturated
    }
    int p = (ty0 + (lane >> 3)) * 128 + tx0 + (lane & 7);
    out[p * 3 + 0] = oR;
    out[p * 3 + 1] = oG;
    out[p * 3 + 2] = oB;
}

extern "C" void kernel_launch(void* const* d_in, const int* in_sizes, int n_in,
                              void* d_out, int out_size, void* d_ws, size_t ws_size,
                              hipStream_t stream)
{
    const float* x       = (const float*)d_in[0];
    const float* pts     = (const float*)d_in[1];
    const float* viewmat = (const float*)d_in[2];
    const float* w_shs   = (const float*)d_in[3];
    const float* b_shs   = (const float*)d_in[4];
    const float* w_scale = (const float*)d_in[5];
    const float* b_scale = (const float*)d_in[6];
    const float* w_xyz   = (const float*)d_in[7];
    const float* b_xyz   = (const float*)d_in[8];
    const float* w_opac  = (const float*)d_in[9];
    const float* b_opac  = (const float*)d_in[10];
    const float* w_rot   = (const float*)d_in[11];
    const float* b_rot   = (const float*)d_in[12];
    float* ws = (float*)d_ws;
    float* out = (float*)d_out;

    k_pre<<<NG / 64, 64, 0, stream>>>(x, pts, viewmat, w_shs, b_shs, w_scale, b_scale,
                                      w_xyz, b_xyz, w_opac, b_opac, w_rot, b_rot, ws);
    k_render<<<256, 64, 0, stream>>>(ws, out);
}

// Round 9
// 47.923 us; speedup vs baseline: 1.7675x; 1.7675x over previous
//
#include <hip/hip_runtime.h>
#include <math.h>

#define NG 2048
#define FEATN 128
#define LOG2E 1.4426950408889634f

typedef unsigned long long u64;

// ws float4-offsets: RAW_A f4[0..2048) {u,v,rx,ry} | RAW_B f4[2048..4096) {a2,b2,c2,op}
//                    RAW_C f4[4096..6144) {r,g,b,0} | TZ float[24576..26624)
#define TZ_FOFF 24576

__device__ __forceinline__ float sigmoidf_(float z) { return 1.0f / (1.0f + expf(-z)); }

__global__ __launch_bounds__(64) void k_pre(
    const float* __restrict__ x, const float* __restrict__ pts, const float* __restrict__ vm,
    const float* __restrict__ w_shs, const float* __restrict__ b_shs,
    const float* __restrict__ w_scale, const float* __restrict__ b_scale,
    const float* __restrict__ w_xyz, const float* __restrict__ b_xyz,
    const float* __restrict__ w_opac, const float* __restrict__ b_opac,
    const float* __restrict__ w_rot, const float* __restrict__ b_rot,
    float* __restrict__ ws)
{
    __shared__ float sw[14 * FEATN];
    int tid = threadIdx.x;
    for (int i = tid; i < 14 * FEATN; i += 64) {
        int r = i >> 7, c0 = i & 127;
        float v;
        if (r < 3)       v = w_shs[r * FEATN + c0];
        else if (r < 6)  v = w_scale[(r - 3) * FEATN + c0];
        else if (r < 9)  v = w_xyz[(r - 6) * FEATN + c0];
        else if (r == 9) v = w_opac[c0];
        else             v = w_rot[(r - 10) * FEATN + c0];
        sw[i] = v;
    }
    __syncthreads();
    int g = blockIdx.x * 64 + tid;

    float acc[14];
#pragma unroll
    for (int j = 0; j < 14; j++) acc[j] = 0.0f;
    const float4* x4 = (const float4*)(x + (size_t)g * FEATN);
#pragma unroll 4
    for (int k4 = 0; k4 < FEATN / 4; k4++) {
        float4 xv = x4[k4];
#pragma unroll
        for (int j = 0; j < 14; j++) {
            const float* wr = &sw[j * FEATN + k4 * 4];
            acc[j] += xv.x * wr[0] + xv.y * wr[1] + xv.z * wr[2] + xv.w * wr[3];
        }
    }

    float r0 = sigmoidf_(acc[0] + b_shs[0]);
    float r1 = sigmoidf_(acc[1] + b_shs[1]);
    float r2 = sigmoidf_(acc[2] + b_shs[2]);
    float s0 = fminf(expf(acc[3] + b_scale[0]), 0.2f);
    float s1 = fminf(expf(acc[4] + b_scale[1]), 0.2f);
    float s2 = fminf(expf(acc[5] + b_scale[2]), 0.2f);
    float o0 = (sigmoidf_(acc[6] + b_xyz[0]) - 0.5f) * 0.05f;
    float o1 = (sigmoidf_(acc[7] + b_xyz[1]) - 0.5f) * 0.05f;
    float o2 = (sigmoidf_(acc[8] + b_xyz[2]) - 0.5f) * 0.05f;
    float opac = sigmoidf_(acc[9] + b_opac[0]);
    float qw = acc[10] + b_rot[0];
    float qx = acc[11] + b_rot[1];
    float qy = acc[12] + b_rot[2];
    float qz = acc[13] + b_rot[3];
    float qn = sqrtf(qw * qw + qx * qx + qy * qy + qz * qz);
    qw /= qn; qx /= qn; qy /= qn; qz /= qn;

    float R[3][3];
    R[0][0] = 1.f - 2.f * (qy * qy + qz * qz);
    R[0][1] = 2.f * (qx * qy - qw * qz);
    R[0][2] = 2.f * (qx * qz + qw * qy);
    R[1][0] = 2.f * (qx * qy + qw * qz);
    R[1][1] = 1.f - 2.f * (qx * qx + qz * qz);
    R[1][2] = 2.f * (qy * qz - qw * qx);
    R[2][0] = 2.f * (qx * qz - qw * qy);
    R[2][1] = 2.f * (qy * qz + qw * qx);
    R[2][2] = 1.f - 2.f * (qx * qx + qy * qy);

    float sq[3] = { s0 * s0, s1 * s1, s2 * s2 };
    float cov[3][3];
#pragma unroll
    for (int i = 0; i < 3; i++)
#pragma unroll
        for (int k = 0; k < 3; k++)
            cov[i][k] = R[i][0] * sq[0] * R[k][0] + R[i][1] * sq[1] * R[k][1] + R[i][2] * sq[2] * R[k][2];

    float Rv[3][3], tv[3];
#pragma unroll
    for (int i = 0; i < 3; i++) {
#pragma unroll
        for (int j = 0; j < 3; j++) Rv[i][j] = vm[i * 4 + j];
        tv[i] = vm[i * 4 + 3];
    }
    float X0 = pts[g * 3 + 0] + o0;
    float X1 = pts[g * 3 + 1] + o1;
    float X2 = pts[g * 3 + 2] + o2;
    float p0 = Rv[0][0] * X0 + Rv[0][1] * X1 + Rv[0][2] * X2 + tv[0];
    float p1 = Rv[1][0] * X0 + Rv[1][1] * X1 + Rv[1][2] * X2 + tv[1];
    float p2 = Rv[2][0] * X0 + Rv[2][1] * X1 + Rv[2][2] * X2 + tv[2];
    float tz = fmaxf(p2, 0.001f);
    float u = 128.0f * p0 / tz + 64.0f;
    float v = 128.0f * p1 / tz + 64.0f;

    float j00 = 128.0f / tz, j02 = -128.0f * p0 / (tz * tz);
    float j11 = 128.0f / tz, j12 = -128.0f * p1 / (tz * tz);
    float M0[3], M1[3];
#pragma unroll
    for (int k = 0; k < 3; k++) {
        M0[k] = j00 * Rv[0][k] + j02 * Rv[2][k];
        M1[k] = j11 * Rv[1][k] + j12 * Rv[2][k];
    }
    float t0[3], t1[3];
#pragma unroll
    for (int k = 0; k < 3; k++) {
        t0[k] = M0[0] * cov[0][k] + M0[1] * cov[1][k] + M0[2] * cov[2][k];
        t1[k] = M1[0] * cov[0][k] + M1[1] * cov[1][k] + M1[2] * cov[2][k];
    }
    float A = t0[0] * M0[0] + t0[1] * M0[1] + t0[2] * M0[2] + 0.3f;
    float B = t0[0] * M1[0] + t0[1] * M1[1] + t0[2] * M1[2];
    float C = t1[0] * M1[0] + t1[1] * M1[1] + t1[2] * M1[2] + 0.3f;
    float det = A * C - B * B + 1e-12f;
    float cA = C / det, cB = -B / det, cC = A / det;

    if (p2 <= 0.01f) opac = 0.0f;   // vis mask folded into opacity

    // conservative bounding half-extents for alpha >= 1/255
    float rx, ry;
    if (opac >= 1.0f / 255.0f) {
        float L = 2.0f * logf(255.0f * opac);
        rx = sqrtf(L * A) + 0.5f;
        ry = sqrtf(L * C) + 0.5f;
    } else {
        rx = -1e9f; ry = -1e9f;   // never kept
    }

    float4* ws4 = (float4*)ws;
    ws4[0 * NG + g] = make_float4(u, v, rx, ry);
    ws4[1 * NG + g] = make_float4(-0.5f * LOG2E * cA, -LOG2E * cB, -0.5f * LOG2E * cC, opac);
    ws4[2 * NG + g] = make_float4(r0, r1, r2, 0.0f);
    ws[TZ_FOFF + g] = tz;
}

// one 256-thread block (4 waves) per 8x8 tile:
//   cull (order-free) -> 256-wide rank sort -> depth-segmented composite across
//   4 waves -> associative over-operator combine.
__global__ __launch_bounds__(256) void k_render(const float* __restrict__ ws, float* __restrict__ out)
{
    __shared__ u64 slist[NG];          // survivor keys (tz_bits<<32 | g)
    __shared__ int sort_g[NG];         // depth-ordered survivor indices
    __shared__ float comp[4][64 * 12]; // per-wave staged params
    __shared__ float partT[4][64], partR[4][64], partG[4][64], partB[4][64];
    __shared__ int s_cnt[4];

    const int tid = threadIdx.x;
    const int wid = tid >> 6, lane = tid & 63;
    const int bid = blockIdx.x;
    const float4* RA = (const float4*)ws;
    const float4* RB = RA + NG;
    const float4* RC = RA + 2 * NG;
    const float* TZ = ws + TZ_FOFF;

    int tx0 = (bid & 15) << 3, ty0 = (bid >> 4) << 3;
    float x0 = tx0 + 0.5f, x1 = tx0 + 7.5f;
    float y0 = ty0 + 0.5f, y1 = ty0 + 7.5f;
    u64 lmask = (1ull << lane) - 1ull;

    // ---- cull: 8 rounds of 256-wide scans; append (order irrelevant, sort follows)
    int n = 0;
    for (int r = 0; r < NG / 256; ++r) {
        int g = r * 256 + tid;
        float4 a = RA[g];
        float tz = TZ[g];
        bool keep = (a.x + a.z >= x0) && (a.x - a.z <= x1) &&
                    (a.y + a.w >= y0) && (a.y - a.w <= y1);
        u64 m = __ballot(keep);
        if (lane == 0) s_cnt[wid] = __popcll(m);
        __syncthreads();
        int base = n;
#pragma unroll
        for (int w = 0; w < 4; w++) if (w < wid) base += s_cnt[w];
        int total = s_cnt[0] + s_cnt[1] + s_cnt[2] + s_cnt[3];
        if (keep) {
            int pos = base + __popcll(m & lmask);
            slist[pos] = ((u64)__float_as_uint(tz) << 32) | (unsigned)g;
        }
        n += total;
        __syncthreads();
    }

    // ---- 256-wide stable rank sort (keys distinct: g in low bits) ----
    for (int i = tid; i < n; i += 256) {
        u64 ki = slist[i];
        int cnt = 0;
        int j = 0;
        for (; j + 4 <= n; j += 4) {
            cnt += (slist[j + 0] < ki) ? 1 : 0;
            cnt += (slist[j + 1] < ki) ? 1 : 0;
            cnt += (slist[j + 2] < ki) ? 1 : 0;
            cnt += (slist[j + 3] < ki) ? 1 : 0;
        }
        for (; j < n; ++j) cnt += (slist[j] < ki) ? 1 : 0;
        sort_g[cnt] = (int)(unsigned)(ki & 0xffffffffu);
    }
    __syncthreads();

    // ---- depth-segmented composite: wave w owns sorted segment w ----
    int seg = (n + 3) >> 2;                 // ceil(n/4)
    int sbeg = wid * seg;
    int send = min(n, sbeg + seg);
    int rounds = (seg + 63) >> 6;           // uniform across waves
    float gx = x0 + (float)(lane & 7);
    float gy = y0 + (float)(lane >> 3);
    float T = 1.0f, oR = 0.0f, oG = 0.0f, oB = 0.0f;

    for (int t = 0; t < rounds; ++t) {
        int idx = sbeg + t * 64 + lane;
        if (idx < send) {
            int g = sort_g[idx];
            float4 a = RA[g];
            float4 b = RB[g];
            float4 c = RC[g];
            float* e = &comp[wid][lane * 12];
            ((float4*)e)[0] = make_float4(a.x, a.y, b.x, b.y);   // u,v,a2,b2
            ((float4*)e)[1] = make_float4(b.z, b.w, c.x, c.y);   // c2,op,r,g
            e[8] = c.z;                                          // b
        }
        __syncthreads();
        int nr = send - (sbeg + t * 64);
        nr = (nr < 0) ? 0 : ((nr > 64) ? 64 : nr);
        for (int i = 0; i < nr; ++i) {
            const float* e = &comp[wid][i * 12];
            float4 e0 = ((const float4*)e)[0];
            float4 e1 = ((const float4*)e)[1];
            float bl = e[8];
            float dx = gx - e0.x, dy = gy - e0.y;
            float pw = dx * (e0.z * dx + e0.w * dy) + e1.x * dy * dy;  // log2-domain
            pw = fminf(pw, 0.0f);
            float al = fminf(0.99f, e1.y * exp2f(pw));
            al = (al < 1.0f / 255.0f) ? 0.0f : al;
            float w = al * T;
            oR += w * e1.z;
            oG += w * e1.w;
            oB += w * bl;
            T -= al * T;
        }
        __syncthreads();
    }

    partT[wid][lane] = T;
    partR[wid][lane] = oR;
    partG[wid][lane] = oG;
    partB[wid][lane] = oB;
    __syncthreads();

    if (wid == 0) {
        float Tp = 1.0f, fR = 0.0f, fG = 0.0f, fB = 0.0f;
#pragma unroll
        for (int w = 0; w < 4; w++) {
            fR += Tp * partR[w][lane];
            fG += Tp * partG[w][lane];
            fB += Tp * partB[w][lane];
            Tp *= partT[w][lane];
        }
        int p = (ty0 + (lane >> 3)) * 128 + tx0 + (lane & 7);
        out[p * 3 + 0] = fR;
        out[p * 3 + 1] = fG;
        out[p * 3 + 2] = fB;
    }
}

extern "C" void kernel_launch(void* const* d_in, const int* in_sizes, int n_in,
                              void* d_out, int out_size, void* d_ws, size_t ws_size,
                              hipStream_t stream)
{
    const float* x       = (const float*)d_in[0];
    const float* pts     = (const float*)d_in[1];
    const float* viewmat = (const float*)d_in[2];
    const float* w_shs   = (const float*)d_in[3];
    const float* b_shs   = (const float*)d_in[4];
    const float* w_scale = (const float*)d_in[5];
    const float* b_scale = (const float*)d_in[6];
    const float* w_xyz   = (const float*)d_in[7];
    const float* b_xyz   = (const float*)d_in[8];
    const float* w_opac  = (const float*)d_in[9];
    const float* b_opac  = (const float*)d_in[10];
    const float* w_rot   = (const float*)d_in[11];
    const float* b_rot   = (const float*)d_in[12];
    float* ws = (float*)d_ws;
    float* out = (float*)d_out;

    k_pre<<<NG / 64, 64, 0, stream>>>(x, pts, viewmat, w_shs, b_shs, w_scale, b_scale,
                                      w_xyz, b_xyz, w_opac, b_opac, w_rot, b_rot, ws);
    k_render<<<256, 256, 0, stream>>>(ws, out);
}